// Round 5
// baseline (1345.442 us; speedup 1.0000x reference)
//
#include <hip/hip_runtime.h>
#include <hip/hip_bf16.h>

typedef __bf16 bf16;
typedef __bf16 bf16x8 __attribute__((ext_vector_type(8)));
typedef __bf16 bf16x4 __attribute__((ext_vector_type(4)));
typedef float f32x4 __attribute__((ext_vector_type(4)));

#define NT 8192   // tokens = B*S
#define DD 1024   // model dim
#define HH 4096   // hidden dim
#define NE 8      // experts

__device__ __forceinline__ void gload_lds16(const void* g, void* l) {
  __builtin_amdgcn_global_load_lds(
      (__attribute__((address_space(1))) void*)(g),
      (__attribute__((address_space(3))) void*)(l), 16, 0, 0);
}

// ------------- [E][R][C] f32 -> [E][C][R] bf16 -------------
__global__ void k_transpose(const float* __restrict__ in, bf16* __restrict__ out,
                            int R, int C) {
  __shared__ float tile[32][33];
  int e = blockIdx.z;
  int c0 = blockIdx.x * 32, r0 = blockIdx.y * 32;
  int tx = threadIdx.x, ty = threadIdx.y;  // 32 x 8
  const float* ip = in + (size_t)e * R * C;
  bf16* op = out + (size_t)e * R * C;
#pragma unroll
  for (int i = 0; i < 4; ++i)
    tile[ty + i * 8][tx] = ip[(size_t)(r0 + ty + i * 8) * C + c0 + tx];
  __syncthreads();
#pragma unroll
  for (int i = 0; i < 4; ++i)
    op[(size_t)(c0 + ty + i * 8) * R + r0 + tx] = (bf16)tile[tx][ty + i * 8];
}

// ---------------- router (+ fused x -> bf16 conversion) ----------------
__global__ __launch_bounds__(256) void k_router(
    const float* __restrict__ x, const float* __restrict__ Wr,
    bf16* __restrict__ xb,
    float* __restrict__ gate, int* __restrict__ lists, int* __restrict__ counts,
    float* __restrict__ auxpart) {
  __shared__ float bp[4][8];
  int wv = threadIdx.x >> 6, l = threadIdx.x & 63;
  int t = blockIdx.x * 4 + wv;
  const float* xr = x + (size_t)t * DD;
  bf16* xbr = xb + (size_t)t * DD;
  float p[8];
#pragma unroll
  for (int e = 0; e < 8; ++e) p[e] = 0.f;
#pragma unroll
  for (int c = 0; c < 4; ++c) {
    int d0 = c * 256 + l * 4;
    float4 xv = *reinterpret_cast<const float4*>(xr + d0);
    bf16x4 o;
    o[0] = (bf16)xv.x; o[1] = (bf16)xv.y; o[2] = (bf16)xv.z; o[3] = (bf16)xv.w;
    *reinterpret_cast<bf16x4*>(xbr + d0) = o;
    float xs[4] = {xv.x, xv.y, xv.z, xv.w};
#pragma unroll
    for (int j = 0; j < 4; ++j) {
      float4 w0 = *reinterpret_cast<const float4*>(Wr + (size_t)(d0 + j) * 8);
      float4 w1 = *reinterpret_cast<const float4*>(Wr + (size_t)(d0 + j) * 8 + 4);
      p[0] += xs[j] * w0.x; p[1] += xs[j] * w0.y;
      p[2] += xs[j] * w0.z; p[3] += xs[j] * w0.w;
      p[4] += xs[j] * w1.x; p[5] += xs[j] * w1.y;
      p[6] += xs[j] * w1.z; p[7] += xs[j] * w1.w;
    }
  }
#pragma unroll
  for (int off = 32; off >= 1; off >>= 1)
#pragma unroll
    for (int e = 0; e < 8; ++e) p[e] += __shfl_down(p[e], off);
  if (l == 0) {
    float m = p[0];
#pragma unroll
    for (int e = 1; e < 8; ++e) m = fmaxf(m, p[e]);
    float pr[8], s = 0.f;
#pragma unroll
    for (int e = 0; e < 8; ++e) { pr[e] = expf(p[e] - m); s += pr[e]; }
    float inv = 1.f / s;
#pragma unroll
    for (int e = 0; e < 8; ++e) pr[e] *= inv;
    int i1 = 0;
#pragma unroll
    for (int e = 1; e < 8; ++e) if (pr[e] > pr[i1]) i1 = e;
    int i2 = (i1 == 0) ? 1 : 0;
#pragma unroll
    for (int e = 0; e < 8; ++e) if (e != i1 && pr[e] > pr[i2]) i2 = e;
    float wsum = pr[i1] + pr[i2];
    gate[t * 8 + i1] = pr[i1] / wsum;
    gate[t * 8 + i2] = pr[i2] / wsum;
    int p1 = atomicAdd(&counts[i1], 1); lists[i1 * NT + p1] = t;
    int p2 = atomicAdd(&counts[i2], 1); lists[i2 * NT + p2] = t;
#pragma unroll
    for (int e = 0; e < 8; ++e) bp[wv][e] = pr[e];
  }
  __syncthreads();
  if (threadIdx.x < 8) {
    float s = bp[0][threadIdx.x] + bp[1][threadIdx.x] +
              bp[2][threadIdx.x] + bp[3][threadIdx.x];
    auxpart[blockIdx.x * 8 + threadIdx.x] = s;
  }
}

// ------------- aux loss + prefix offsets -------------
__global__ void k_finalize(const int* __restrict__ counts, int* __restrict__ offs,
                           const float* __restrict__ auxpart, float* __restrict__ aux_out) {
  __shared__ float sh[32][8];
  int e = threadIdx.x & 7, chunk = threadIdx.x >> 3;  // 256 threads
  float s = 0.f;
  for (int b = chunk * 64; b < chunk * 64 + 64; ++b) s += auxpart[b * 8 + e];
  sh[chunk][e] = s;
  __syncthreads();
  if (threadIdx.x < 8) {
    float tot = 0.f;
    for (int c = 0; c < 32; ++c) tot += sh[c][threadIdx.x];
    float d = tot * (1.f / 8192.f) - 0.125f;
    sh[0][threadIdx.x] = d * d;
  }
  __syncthreads();
  if (threadIdx.x == 0) {
    float loss = 0.f;
    for (int e2 = 0; e2 < 8; ++e2) loss += sh[0][e2];
    aux_out[0] = loss;
    int o = 0;
    for (int e2 = 0; e2 < 8; ++e2) { offs[e2] = o; o += counts[e2]; }
    offs[8] = o;
  }
}

// ------------- grouped expert GEMM (128x128 tile, BK=64) + XCD swizzle -------------
// C[M x NTOT] = A[M x KTOT] @ B^T (B stored [NTOT][KTOT] bf16, contiguous K)
// IS_G1: A rows gathered via token list; epilogue = exact GELU -> bf16 H
// !IS_G1: A = H rows; epilogue = gate-weighted atomic add into f32 out
// R5: per-expert (x,y) grid flattened and XCD-chunk-swizzled so the 8 XCDs get
// contiguous runs of logical blocks (A-panel 256KB L2-resident per XCD).
template <int KTOT, int NTOT, bool IS_G1>
__global__ __launch_bounds__(256, 2) void k_moe_gemm(
    const bf16* __restrict__ A, const bf16* __restrict__ Bw,
    bf16* __restrict__ Hout, float* __restrict__ Yout,
    const int* __restrict__ lists, const int* __restrict__ counts,
    const int* __restrict__ offs, const float* __restrict__ gate) {
  const int e = blockIdx.z;
  const int count = counts[e];

  // XCD-chunked bijective swizzle within the expert's (x,y) grid
  const int nx = NTOT / 128;          // 32 (G1) or 8 (G2)
  const int NW = nx * 64;             // per-expert blocks, divisible by 8
  const int d = blockIdx.x + nx * blockIdx.y;
  const int swz = (d & 7) * (NW >> 3) + (d >> 3);
  const int bx = swz % nx, by = swz / nx;

  const int m0 = by * 128;
  if (m0 >= count) return;
  const int n0 = bx * 128;
  const int tid = threadIdx.x;
  const int w = tid >> 6, l = tid & 63;

  __shared__ __align__(16) char lds[32768];  // As [0,16K), Bs [16K,32K)

  const int hoff = offs[e];
  // staging: lane covers row r=(i*4+w)*8 + (l>>3), 16B chunk (l&7); source col
  // pre-swizzled so that swizzled ds_read sees logical layout (rule #21)
  const int sr = l >> 3;
  const int scol = ((l & 7) ^ sr) << 3;  // elems
  const bf16* aptr[4];
  const bf16* bptr[4];
#pragma unroll
  for (int i = 0; i < 4; ++i) {
    int r = (i * 4 + w) * 8 + sr;
    int mrow = m0 + r; if (mrow > count - 1) mrow = count - 1;
    size_t arow = IS_G1 ? (size_t)lists[e * NT + mrow] : (size_t)(hoff + mrow);
    aptr[i] = A + arow * KTOT + scol;
    bptr[i] = Bw + (size_t)e * NTOT * KTOT + (size_t)(n0 + r) * KTOT + scol;
  }

  f32x4 acc[4][4];
#pragma unroll
  for (int mi = 0; mi < 4; ++mi)
#pragma unroll
    for (int ni = 0; ni < 4; ++ni) acc[mi][ni] = (f32x4){0.f, 0.f, 0.f, 0.f};

  // stage k-tile 0
#pragma unroll
  for (int i = 0; i < 4; ++i) gload_lds16(aptr[i], &lds[(i * 4 + w) * 1024]);
#pragma unroll
  for (int i = 0; i < 4; ++i) gload_lds16(bptr[i], &lds[16384 + (i * 4 + w) * 1024]);

  const int wm = w >> 1, wn = w & 1;
  const int lr = l & 15, lk = l >> 4;
  const int cb = (lk * 16) ^ ((l & 7) << 4);  // swizzled byte col
  const int abase = (wm * 64 + lr) * 128 + cb;
  const int bbase = 16384 + (wn * 64 + lr) * 128 + cb;

  const int NKT = KTOT / 64;
  for (int kt = 0; kt < NKT; ++kt) {
    asm volatile("s_waitcnt vmcnt(0)" ::: "memory");
    __syncthreads();
#pragma unroll
    for (int ks = 0; ks < 2; ++ks) {
      bf16x8 af[4], bfr[4];
#pragma unroll
      for (int mi = 0; mi < 4; ++mi)
        af[mi] = *reinterpret_cast<const bf16x8*>(&lds[(abase + mi * 2048) ^ (ks << 6)]);
#pragma unroll
      for (int ni = 0; ni < 4; ++ni)
        bfr[ni] = *reinterpret_cast<const bf16x8*>(&lds[(bbase + ni * 2048) ^ (ks << 6)]);
#pragma unroll
      for (int mi = 0; mi < 4; ++mi)
#pragma unroll
        for (int ni = 0; ni < 4; ++ni)
          acc[mi][ni] = __builtin_amdgcn_mfma_f32_16x16x32_bf16(
              af[mi], bfr[ni], acc[mi][ni], 0, 0, 0);
    }
    __syncthreads();
    if (kt + 1 < NKT) {
#pragma unroll
      for (int i = 0; i < 4; ++i) {
        aptr[i] += 64; gload_lds16(aptr[i], &lds[(i * 4 + w) * 1024]);
      }
#pragma unroll
      for (int i = 0; i < 4; ++i) {
        bptr[i] += 64; gload_lds16(bptr[i], &lds[16384 + (i * 4 + w) * 1024]);
      }
    }
  }

  // epilogue: C[m][n], m=(l>>4)*4+j (+16*mi), n=l&15 (+16*ni) within wave tile
#pragma unroll
  for (int mi = 0; mi < 4; ++mi) {
#pragma unroll
    for (int j = 0; j < 4; ++j) {
      int row = wm * 64 + mi * 16 + lk * 4 + j;
      int m = m0 + row;
      if (m < count) {
        if (IS_G1) {
          size_t base = (size_t)(hoff + m) * NTOT + n0 + wn * 64 + lr;
#pragma unroll
          for (int ni = 0; ni < 4; ++ni) {
            float v = acc[mi][ni][j];
            float g = 0.5f * v * (1.0f + erff(v * 0.70710678118654752f));
            Hout[base + ni * 16] = (bf16)g;
          }
        } else {
          int tok = lists[e * NT + m];
          float wg = gate[tok * 8 + e];
          size_t base = (size_t)tok * 1024 + n0 + wn * 64 + lr;
#pragma unroll
          for (int ni = 0; ni < 4; ++ni)
            unsafeAtomicAdd(&Yout[base + ni * 16], wg * acc[mi][ni][j]);
        }
      }
    }
  }
}

extern "C" void kernel_launch(void* const* d_in, const int* in_sizes, int n_in,
                              void* d_out, int out_size, void* d_ws, size_t ws_size,
                              hipStream_t stream) {
  const float* x = (const float*)d_in[0];
  const float* Wr = (const float*)d_in[1];
  const float* W1 = (const float*)d_in[2];
  const float* W2 = (const float*)d_in[3];
  float* out = (float*)d_out;

  char* ws = (char*)d_ws;
  size_t off = 0;
  bf16* Xb = (bf16*)(ws + off);  off += (size_t)NT * DD * 2;        // 16.8 MB
  bf16* W1T = (bf16*)(ws + off); off += (size_t)NE * DD * HH * 2;   // 67 MB
  bf16* W2T = (bf16*)(ws + off); off += (size_t)NE * DD * HH * 2;   // 67 MB
  bf16* Hb = (bf16*)(ws + off);  off += (size_t)NT * 2 * HH * 2;    // 134 MB (16384 rows)
  float* gate = (float*)(ws + off); off += (size_t)NT * 8 * 4;
  int* lists = (int*)(ws + off);    off += (size_t)NE * NT * 4;
  int* counts = (int*)(ws + off);   off += 64;
  int* offs = (int*)(ws + off);     off += 64;
  float* auxpart = (float*)(ws + off); off += (size_t)(NT / 4) * 8 * 4;

  hipMemsetAsync(d_out, 0, (size_t)out_size * 4, stream);
  hipMemsetAsync(counts, 0, 64, stream);

  k_transpose<<<dim3(HH / 32, DD / 32, NE), dim3(32, 8), 0, stream>>>(W1, W1T, DD, HH);
  k_transpose<<<dim3(DD / 32, HH / 32, NE), dim3(32, 8), 0, stream>>>(W2, W2T, HH, DD);
  k_router<<<NT / 4, 256, 0, stream>>>(x, Wr, Xb, gate, lists, counts, auxpart);
  k_finalize<<<1, 256, 0, stream>>>(counts, offs, auxpart, out + (size_t)NT * DD);
  k_moe_gemm<DD, HH, true><<<dim3(HH / 128, 64, NE), 256, 0, stream>>>(
      Xb, W1T, Hb, nullptr, lists, counts, offs, gate);
  k_moe_gemm<HH, DD, false><<<dim3(DD / 128, 64, NE), 256, 0, stream>>>(
      Hb, W2T, nullptr, out, lists, counts, offs, gate);
}

// Round 6
// 690.318 us; speedup vs baseline: 1.9490x; 1.9490x over previous
//
#include <hip/hip_runtime.h>
#include <hip/hip_bf16.h>

typedef __bf16 bf16;
typedef __bf16 bf16x8 __attribute__((ext_vector_type(8)));
typedef __bf16 bf16x4 __attribute__((ext_vector_type(4)));
typedef float f32x4 __attribute__((ext_vector_type(4)));

#define NT 8192   // tokens = B*S
#define DD 1024   // model dim
#define HH 4096   // hidden dim
#define NE 8      // experts

__device__ __forceinline__ void gload_lds16(const void* g, void* l) {
  __builtin_amdgcn_global_load_lds(
      (__attribute__((address_space(1))) void*)(g),
      (__attribute__((address_space(3))) void*)(l), 16, 0, 0);
}

// ------------- [E][R][C] f32 -> [E][C][R] bf16 -------------
__global__ void k_transpose(const float* __restrict__ in, bf16* __restrict__ out,
                            int R, int C) {
  __shared__ float tile[32][33];
  int e = blockIdx.z;
  int c0 = blockIdx.x * 32, r0 = blockIdx.y * 32;
  int tx = threadIdx.x, ty = threadIdx.y;  // 32 x 8
  const float* ip = in + (size_t)e * R * C;
  bf16* op = out + (size_t)e * R * C;
#pragma unroll
  for (int i = 0; i < 4; ++i)
    tile[ty + i * 8][tx] = ip[(size_t)(r0 + ty + i * 8) * C + c0 + tx];
  __syncthreads();
#pragma unroll
  for (int i = 0; i < 4; ++i)
    op[(size_t)(c0 + ty + i * 8) * R + r0 + tx] = (bf16)tile[tx][ty + i * 8];
}

// ---------------- router (+ fused x -> bf16 conversion) ----------------
__global__ __launch_bounds__(256) void k_router(
    const float* __restrict__ x, const float* __restrict__ Wr,
    bf16* __restrict__ xb,
    float* __restrict__ gate, int* __restrict__ lists, int* __restrict__ counts,
    float* __restrict__ auxpart) {
  __shared__ float bp[4][8];
  int wv = threadIdx.x >> 6, l = threadIdx.x & 63;
  int t = blockIdx.x * 4 + wv;
  const float* xr = x + (size_t)t * DD;
  bf16* xbr = xb + (size_t)t * DD;
  float p[8];
#pragma unroll
  for (int e = 0; e < 8; ++e) p[e] = 0.f;
#pragma unroll
  for (int c = 0; c < 4; ++c) {
    int d0 = c * 256 + l * 4;
    float4 xv = *reinterpret_cast<const float4*>(xr + d0);
    bf16x4 o;
    o[0] = (bf16)xv.x; o[1] = (bf16)xv.y; o[2] = (bf16)xv.z; o[3] = (bf16)xv.w;
    *reinterpret_cast<bf16x4*>(xbr + d0) = o;
    float xs[4] = {xv.x, xv.y, xv.z, xv.w};
#pragma unroll
    for (int j = 0; j < 4; ++j) {
      float4 w0 = *reinterpret_cast<const float4*>(Wr + (size_t)(d0 + j) * 8);
      float4 w1 = *reinterpret_cast<const float4*>(Wr + (size_t)(d0 + j) * 8 + 4);
      p[0] += xs[j] * w0.x; p[1] += xs[j] * w0.y;
      p[2] += xs[j] * w0.z; p[3] += xs[j] * w0.w;
      p[4] += xs[j] * w1.x; p[5] += xs[j] * w1.y;
      p[6] += xs[j] * w1.z; p[7] += xs[j] * w1.w;
    }
  }
#pragma unroll
  for (int off = 32; off >= 1; off >>= 1)
#pragma unroll
    for (int e = 0; e < 8; ++e) p[e] += __shfl_down(p[e], off);
  if (l == 0) {
    float m = p[0];
#pragma unroll
    for (int e = 1; e < 8; ++e) m = fmaxf(m, p[e]);
    float pr[8], s = 0.f;
#pragma unroll
    for (int e = 0; e < 8; ++e) { pr[e] = expf(p[e] - m); s += pr[e]; }
    float inv = 1.f / s;
#pragma unroll
    for (int e = 0; e < 8; ++e) pr[e] *= inv;
    int i1 = 0;
#pragma unroll
    for (int e = 1; e < 8; ++e) if (pr[e] > pr[i1]) i1 = e;
    int i2 = (i1 == 0) ? 1 : 0;
#pragma unroll
    for (int e = 0; e < 8; ++e) if (e != i1 && pr[e] > pr[i2]) i2 = e;
    float wsum = pr[i1] + pr[i2];
    gate[t * 8 + i1] = pr[i1] / wsum;
    gate[t * 8 + i2] = pr[i2] / wsum;
    int p1 = atomicAdd(&counts[i1], 1); lists[i1 * NT + p1] = t;
    int p2 = atomicAdd(&counts[i2], 1); lists[i2 * NT + p2] = t;
#pragma unroll
    for (int e = 0; e < 8; ++e) bp[wv][e] = pr[e];
  }
  __syncthreads();
  if (threadIdx.x < 8) {
    float s = bp[0][threadIdx.x] + bp[1][threadIdx.x] +
              bp[2][threadIdx.x] + bp[3][threadIdx.x];
    auxpart[blockIdx.x * 8 + threadIdx.x] = s;
  }
}

// ------------- aux loss + prefix offsets -------------
__global__ void k_finalize(const int* __restrict__ counts, int* __restrict__ offs,
                           const float* __restrict__ auxpart, float* __restrict__ aux_out) {
  __shared__ float sh[32][8];
  int e = threadIdx.x & 7, chunk = threadIdx.x >> 3;  // 256 threads
  float s = 0.f;
  for (int b = chunk * 64; b < chunk * 64 + 64; ++b) s += auxpart[b * 8 + e];
  sh[chunk][e] = s;
  __syncthreads();
  if (threadIdx.x < 8) {
    float tot = 0.f;
    for (int c = 0; c < 32; ++c) tot += sh[c][threadIdx.x];
    float d = tot * (1.f / 8192.f) - 0.125f;
    sh[0][threadIdx.x] = d * d;
  }
  __syncthreads();
  if (threadIdx.x == 0) {
    float loss = 0.f;
    for (int e2 = 0; e2 < 8; ++e2) loss += sh[0][e2];
    aux_out[0] = loss;
    int o = 0;
    for (int e2 = 0; e2 < 8; ++e2) { offs[e2] = o; o += counts[e2]; }
    offs[8] = o;
  }
}

// ------------- grouped expert GEMM (128x128 tile, BK=64) + supertiling -------------
// C[M x NTOT] = A[M x KTOT] @ B^T (B stored [NTOT][KTOT] bf16, contiguous K)
// IS_G1: A rows gathered via token list; epilogue = exact GELU -> bf16 H
// !IS_G1: A = H rows; epilogue = gate-weighted atomic add into f32 out
// R6: 1-D grid per expert, remapped into 8x8 supertiles of 128x128 blocks.
// 64 consecutive hw blocks share 8 A-panels + 8 B-panels (4 MB, L2-resident);
// useful blocks stay a contiguous hw prefix (empty m-tiles = contiguous tail).
template <int KTOT, int NTOT, bool IS_G1>
__global__ __launch_bounds__(256, 2) void k_moe_gemm(
    const bf16* __restrict__ A, const bf16* __restrict__ Bw,
    bf16* __restrict__ Hout, float* __restrict__ Yout,
    const int* __restrict__ lists, const int* __restrict__ counts,
    const int* __restrict__ offs, const float* __restrict__ gate) {
  const int e = blockIdx.z;
  const int count = counts[e];

  // supertile remap: d -> (by, bx), useful prefix preserved
  const int nx = NTOT / 128;          // n-tiles: 32 (G1) or 8 (G2)
  const int nsc = nx >> 3;            // n super-cols: 4 or 1
  const int d = blockIdx.x;
  const int super = d >> 6, within = d & 63;
  const int srow = super / nsc, scol = super % nsc;
  const int by = srow * 8 + (within >> 3);
  const int bx = scol * 8 + (within & 7);

  const int m0 = by * 128;
  if (m0 >= count) return;
  const int n0 = bx * 128;
  const int tid = threadIdx.x;
  const int w = tid >> 6, l = tid & 63;

  __shared__ __align__(16) char lds[32768];  // As [0,16K), Bs [16K,32K)

  const int hoff = offs[e];
  // staging: lane covers row r=(i*4+w)*8 + (l>>3), 16B chunk (l&7); source col
  // pre-swizzled so that swizzled ds_read sees logical layout (rule #21)
  const int sr = l >> 3;
  const int scolx = ((l & 7) ^ sr) << 3;  // elems
  const bf16* aptr[4];
  const bf16* bptr[4];
#pragma unroll
  for (int i = 0; i < 4; ++i) {
    int r = (i * 4 + w) * 8 + sr;
    int mrow = m0 + r; if (mrow > count - 1) mrow = count - 1;
    size_t arow = IS_G1 ? (size_t)lists[e * NT + mrow] : (size_t)(hoff + mrow);
    aptr[i] = A + arow * KTOT + scolx;
    bptr[i] = Bw + (size_t)e * NTOT * KTOT + (size_t)(n0 + r) * KTOT + scolx;
  }

  f32x4 acc[4][4];
#pragma unroll
  for (int mi = 0; mi < 4; ++mi)
#pragma unroll
    for (int ni = 0; ni < 4; ++ni) acc[mi][ni] = (f32x4){0.f, 0.f, 0.f, 0.f};

  // stage k-tile 0
#pragma unroll
  for (int i = 0; i < 4; ++i) gload_lds16(aptr[i], &lds[(i * 4 + w) * 1024]);
#pragma unroll
  for (int i = 0; i < 4; ++i) gload_lds16(bptr[i], &lds[16384 + (i * 4 + w) * 1024]);

  const int wm = w >> 1, wn = w & 1;
  const int lr = l & 15, lk = l >> 4;
  const int cb = (lk * 16) ^ ((l & 7) << 4);  // swizzled byte col
  const int abase = (wm * 64 + lr) * 128 + cb;
  const int bbase = 16384 + (wn * 64 + lr) * 128 + cb;

  const int NKT = KTOT / 64;
  for (int kt = 0; kt < NKT; ++kt) {
    asm volatile("s_waitcnt vmcnt(0)" ::: "memory");
    __syncthreads();
#pragma unroll
    for (int ks = 0; ks < 2; ++ks) {
      bf16x8 af[4], bfr[4];
#pragma unroll
      for (int mi = 0; mi < 4; ++mi)
        af[mi] = *reinterpret_cast<const bf16x8*>(&lds[(abase + mi * 2048) ^ (ks << 6)]);
#pragma unroll
      for (int ni = 0; ni < 4; ++ni)
        bfr[ni] = *reinterpret_cast<const bf16x8*>(&lds[(bbase + ni * 2048) ^ (ks << 6)]);
#pragma unroll
      for (int mi = 0; mi < 4; ++mi)
#pragma unroll
        for (int ni = 0; ni < 4; ++ni)
          acc[mi][ni] = __builtin_amdgcn_mfma_f32_16x16x32_bf16(
              af[mi], bfr[ni], acc[mi][ni], 0, 0, 0);
    }
    __syncthreads();
    if (kt + 1 < NKT) {
#pragma unroll
      for (int i = 0; i < 4; ++i) {
        aptr[i] += 64; gload_lds16(aptr[i], &lds[(i * 4 + w) * 1024]);
      }
#pragma unroll
      for (int i = 0; i < 4; ++i) {
        bptr[i] += 64; gload_lds16(bptr[i], &lds[16384 + (i * 4 + w) * 1024]);
      }
    }
  }

  // epilogue: C[m][n], m=(l>>4)*4+j (+16*mi), n=l&15 (+16*ni) within wave tile
#pragma unroll
  for (int mi = 0; mi < 4; ++mi) {
#pragma unroll
    for (int j = 0; j < 4; ++j) {
      int row = wm * 64 + mi * 16 + lk * 4 + j;
      int m = m0 + row;
      if (m < count) {
        if (IS_G1) {
          size_t base = (size_t)(hoff + m) * NTOT + n0 + wn * 64 + lr;
#pragma unroll
          for (int ni = 0; ni < 4; ++ni) {
            float v = acc[mi][ni][j];
            float g = 0.5f * v * (1.0f + erff(v * 0.70710678118654752f));
            Hout[base + ni * 16] = (bf16)g;
          }
        } else {
          int tok = lists[e * NT + m];
          float wg = gate[tok * 8 + e];
          size_t base = (size_t)tok * 1024 + n0 + wn * 64 + lr;
#pragma unroll
          for (int ni = 0; ni < 4; ++ni)
            unsafeAtomicAdd(&Yout[base + ni * 16], wg * acc[mi][ni][j]);
        }
      }
    }
  }
}

extern "C" void kernel_launch(void* const* d_in, const int* in_sizes, int n_in,
                              void* d_out, int out_size, void* d_ws, size_t ws_size,
                              hipStream_t stream) {
  const float* x = (const float*)d_in[0];
  const float* Wr = (const float*)d_in[1];
  const float* W1 = (const float*)d_in[2];
  const float* W2 = (const float*)d_in[3];
  float* out = (float*)d_out;

  char* ws = (char*)d_ws;
  size_t off = 0;
  bf16* Xb = (bf16*)(ws + off);  off += (size_t)NT * DD * 2;        // 16.8 MB
  bf16* W1T = (bf16*)(ws + off); off += (size_t)NE * DD * HH * 2;   // 67 MB
  bf16* W2T = (bf16*)(ws + off); off += (size_t)NE * DD * HH * 2;   // 67 MB
  bf16* Hb = (bf16*)(ws + off);  off += (size_t)NT * 2 * HH * 2;    // 134 MB (16384 rows)
  float* gate = (float*)(ws + off); off += (size_t)NT * 8 * 4;
  int* lists = (int*)(ws + off);    off += (size_t)NE * NT * 4;
  int* counts = (int*)(ws + off);   off += 64;
  int* offs = (int*)(ws + off);     off += 64;
  float* auxpart = (float*)(ws + off); off += (size_t)(NT / 4) * 8 * 4;

  hipMemsetAsync(d_out, 0, (size_t)out_size * 4, stream);
  hipMemsetAsync(counts, 0, 64, stream);

  k_transpose<<<dim3(HH / 32, DD / 32, NE), dim3(32, 8), 0, stream>>>(W1, W1T, DD, HH);
  k_transpose<<<dim3(DD / 32, HH / 32, NE), dim3(32, 8), 0, stream>>>(W2, W2T, HH, DD);
  k_router<<<NT / 4, 256, 0, stream>>>(x, Wr, Xb, gate, lists, counts, auxpart);
  k_finalize<<<1, 256, 0, stream>>>(counts, offs, auxpart, out + (size_t)NT * DD);
  k_moe_gemm<DD, HH, true><<<dim3((HH / 128) * 64, 1, NE), 256, 0, stream>>>(
      Xb, W1T, Hb, nullptr, lists, counts, offs, gate);
  k_moe_gemm<HH, DD, false><<<dim3((DD / 128) * 64, 1, NE), 256, 0, stream>>>(
      Hb, W2T, nullptr, out, lists, counts, offs, gate);
}